// Round 16
// baseline (163.638 us; speedup 1.0000x reference)
//
#include <hip/hip_runtime.h>
#include <hip/hip_bf16.h>

#define NRAYS 8192
#define SAMP  128
#define DVD   27
#define NFEAT 15

typedef float  f32x4  __attribute__((ext_vector_type(4)));
typedef float  f2     __attribute__((ext_vector_type(2)));
typedef short  short8 __attribute__((ext_vector_type(8)));

// fast fp32 -> bf16 (round-half-up): store HIGH short of (bits + 0x8000)
static __device__ __forceinline__ void stbf(short* p, float x) {
    union { unsigned u; struct { short lo, hi; } s; } v;
    v.u = __float_as_uint(x) + 0x8000u;
    *p = v.s.hi;
}
static __device__ __forceinline__ float bf2f(short s) {
    return __uint_as_float(((unsigned)(unsigned short)s) << 16);
}
static __device__ __forceinline__ f2 max2z(f2 a) {
    return __builtin_elementwise_max(a, (f2){0.0f, 0.0f});
}
static __device__ __forceinline__ void sincos_fast(float x, float* s, float* c) {
    float r = x * 0.15915494309189535f;
    r = r - floorf(r);
    *s = __builtin_amdgcn_sinf(r);
    *c = __builtin_amdgcn_cosf(r);
}
static __device__ __forceinline__ float sin_fast(float x) {
    float r = x * 0.15915494309189535f;
    r = r - floorf(r);
    return __builtin_amdgcn_sinf(r);
}
static __device__ __forceinline__ float cos_fast(float x) {
    float r = x * 0.15915494309189535f;
    r = r - floorf(r);
    return __builtin_amdgcn_cosf(r);
}
// double-angle step: (s,c) -> (sin2a, cos2a); uses old s for both outputs
static __device__ __forceinline__ void dbl_angle(float* s, float* c) {
    const float t = (*s) * (*c);
    *c = fmaf(-2.0f * (*s), (*s), 1.0f);
    *s = t + t;
}

// LDS layout (overlay) — R14-proven (32208 B, 5 blk/CU):
//   staging (pre-b2): sW1t@0 [64*72]s 9216B, sW2t@9216 [16*72]s 2304B,
//                     sV1t@11520 [64*32]s 4096B, sV2t@15616 [3*72]s 432B
//   working (post-b2): sE@0 [4][32*72]s 18432B, sG@18432 [4][32*32]s 8192B
//   persistent: sOm@26624 [4][128]f 2048B, sRgb@28672 [4][384]s 3072B,
//               sVde@31744 [4][28]f 448B, sRed@32192 [4]f 16B -> 32208 B
#define SMEM_BYTES 32208

__global__ void __launch_bounds__(256)
march_kernel(const float* __restrict__ orig,
             const float* __restrict__ dirs,
             const float* __restrict__ tmin,
             const float* __restrict__ tmax,
             const float* __restrict__ W1,
             const float* __restrict__ b1,
             const float* __restrict__ W2,
             const float* __restrict__ b2,
             const float* __restrict__ V1,
             const float* __restrict__ c1,
             const float* __restrict__ V2,
             const float* __restrict__ c2,
             float* __restrict__ out) {
    __shared__ __align__(16) char smem[SMEM_BYTES];
    short* const sW1t = (short*)(smem);            // [n*72+k], k<63 real
    short* const sW2t = (short*)(smem + 9216);     // [n*72+k]
    short* const sV1t = (short*)(smem + 11520);    // [n*32+k], k<15 real
    short* const sV2t = (short*)(smem + 15616);    // [n*72+k], n<3
    short* const sEa  = (short*)(smem);            // [wave][32*72]
    short* const sGa  = (short*)(smem + 18432);    // [wave][32*32]
    float* const sOm  = (float*)(smem + 26624);    // [wave][128]
    short* const sRgb = (short*)(smem + 28672);    // [wave][384]
    float* const sVde = (float*)(smem + 31744);    // [wave][28]
    float* const sRed = (float*)(smem + 32192);    // [4]

    const int tid  = threadIdx.x;
    const int lane = tid & 63;
    const int wave = tid >> 6;
    const int ray  = blockIdx.x * 4 + wave;

    // ---- block-redundant dt partial: sum(tmax - tmin) ----
    {
        const float4* tm0 = (const float4*)tmin;
        const float4* tm1 = (const float4*)tmax;
        float s = 0.0f;
        #pragma unroll
        for (int it = 0; it < 8; it++) {
            const int i = tid + it * 256;
            const float4 a = tm1[i], b = tm0[i];
            s += (a.x - b.x) + (a.y - b.y) + (a.z - b.z) + (a.w - b.w);
        }
        #pragma unroll
        for (int off = 32; off > 0; off >>= 1)
            s += __shfl_xor(s, off, 64);
        if (lane == 0) sRed[wave] = s;
    }

    // ---- cooperative weight staging (coalesced global reads) ----
    for (int i = tid; i < 63 * 64; i += 256) {   // W1 [63][64]
        const int k = i >> 6, n = i & 63;
        stbf(&sW1t[n * 72 + k], W1[i]);
    }
    for (int i = tid; i < 64; i += 256) sW1t[i * 72 + 63] = 0;  // pad k=63
    for (int i = tid; i < 64 * 16; i += 256) {   // W2 [64][16]
        const int k = i >> 4, n = i & 15;
        stbf(&sW2t[n * 72 + k], W2[i]);
    }
    for (int i = tid; i < 15 * 64; i += 256) {   // V1 [15][64] (feature rows)
        const int k = i >> 6, n = i & 63;
        stbf(&sV1t[n * 32 + k], V1[i]);
    }
    for (int i = tid; i < 64 * 17; i += 256) {   // V1 pad k=15..31
        const int n = i / 17, k = 15 + (i - 17 * n);
        sV1t[n * 32 + k] = 0;
    }
    for (int i = tid; i < 192; i += 256) {       // V2 [64][3]
        const int k = i / 3, n = i - 3 * k;
        stbf(&sV2t[n * 72 + k], V2[i]);
    }

    // ---- per-ray scalars ----
    const float ox = orig[ray * 3 + 0];
    const float oy = orig[ray * 3 + 1];
    const float oz = orig[ray * 3 + 2];
    const float dx = dirs[ray * 3 + 0];
    const float dy = dirs[ray * 3 + 1];
    const float dz = dirs[ray * 3 + 2];
    const float t0v = tmin[ray];
    const float trange = tmax[ray] - t0v;

    // ---- view-dir encoding (fp32) -> sVde (per-wave) ----
    {
        const float nrm = sqrtf(dx * dx + dy * dy + dz * dz);
        const float inv = 1.0f / (nrm + 1e-8f);
        const float vx = dx * inv, vy = dy * inv, vz = dz * inv;
        if (lane < DVD) {
            float val;
            if (lane < 3) {
                val = (lane == 0) ? vx : ((lane == 1) ? vy : vz);
            } else {
                const int q = lane - 3;
                const int b = q / 6;
                const int r = q - 6 * b;
                const bool isSin = (r < 3);
                const int d = isSin ? r : (r - 3);
                const float comp = (d == 0) ? vx : ((d == 1) ? vy : vz);
                const float a = (float)(1 << b) * comp;
                val = isSin ? sin_fast(a) : cos_fast(a);
            }
            sVde[wave * 28 + lane] = val;
        }
    }
    __syncthreads();   // barrier 1: staging + dt reduce complete

    const float dtv = (sRed[0] + sRed[1] + sRed[2] + sRed[3]) *
                      (1.0f / ((float)NRAYS * (float)SAMP));

    const int nfr  = lane & 15;   // n (or m) within a 16-tile
    const int quad = lane >> 4;

    // ---- build B-fragments from LDS staging (ds_read_b128) ----
    short8 w1f[4][2], w2f[2], v1f[4], v2f[2];
    #pragma unroll
    for (int nt = 0; nt < 4; nt++)
        #pragma unroll
        for (int kt = 0; kt < 2; kt++)
            w1f[nt][kt] = *(const short8*)&sW1t[(nfr + 16 * nt) * 72 + quad * 8 + kt * 32];
    #pragma unroll
    for (int kt = 0; kt < 2; kt++)
        w2f[kt] = *(const short8*)&sW2t[nfr * 72 + quad * 8 + kt * 32];
    #pragma unroll
    for (int nt = 0; nt < 4; nt++)
        v1f[nt] = *(const short8*)&sV1t[(nfr + 16 * nt) * 32 + quad * 8];
    #pragma unroll
    for (int kt = 0; kt < 2; kt++) {
        if (nfr < 3)
            v2f[kt] = *(const short8*)&sV2t[nfr * 72 + quad * 8 + kt * 32];
        else
            v2f[kt] = (short8){0, 0, 0, 0, 0, 0, 0, 0};
    }

    // ---- biases into per-lane registers ----
    float bb1[4], bc1[4];
    #pragma unroll
    for (int nt = 0; nt < 4; nt++) {
        bb1[nt] = b1[nfr + 16 * nt];
        bc1[nt] = c1[nfr + 16 * nt];
    }
    const float bb2 = b2[nfr];
    const float bc2 = (nfr < 3) ? c2[nfr] : 0.0f;

    // ---- gadd[n] = c1[n] + sum_q vde[q] * V1[15+q][n] (fp32, per ray) ----
    float gadd[4];
    #pragma unroll
    for (int nt = 0; nt < 4; nt++) gadd[nt] = bc1[nt];
    #pragma unroll 1
    for (int q = 0; q < DVD; q++) {
        const float e = sVde[wave * 28 + q];
        const float* vrow = V1 + (NFEAT + q) * 64;
        #pragma unroll
        for (int nt = 0; nt < 4; nt++) gadd[nt] += e * vrow[nfr + 16 * nt];
    }
    __syncthreads();   // barrier 2: fragment reads done before sE overwrite

    short* const myE = sEa + wave * (32 * 72);
    short* const myG = sGa + wave * (32 * 32);
    // zero myG (A-side pad must be finite; LDS is undefined at launch)
    {
        int* gz = (int*)myG;
        for (int i = lane; i < 32 * 16; i += 64) gz[i] = 0;
    }

    const int sl   = lane >> 1;   // local sample 0..31 (enc phase)
    const int half = lane & 1;

    #pragma unroll 1
    for (int qq = 0; qq < 4; qq++) {
        // --- positional encodings for 32 samples (2 lanes/sample) ---
        // base band per axis via HW sincos; higher bands via double-angle
        {
            const int s = qq * 32 + sl;
            const float t = t0v + (float)s * (1.0f / 127.0f) * trange;
            const float px = ox + dx * t, py = oy + dy * t, pz = oz + dz * t;
            short* Erow = &myE[sl * 72];
            float sx, cx, sy, cy, sz, cz;
            int base;
            if (half == 0) {
                stbf(&Erow[0], px); stbf(&Erow[1], py); stbf(&Erow[2], pz);
                sincos_fast(px, &sx, &cx);
                sincos_fast(py, &sy, &cy);
                sincos_fast(pz, &sz, &cz);
                base = 0;
            } else {
                sincos_fast(32.0f * px, &sx, &cx);
                sincos_fast(32.0f * py, &sy, &cy);
                sincos_fast(32.0f * pz, &sz, &cz);
                Erow[63] = 0;
                base = 5;
            }
            #pragma unroll
            for (int b = 0; b < 5; b++) {
                short* Eb = &Erow[3 + 6 * (base + b)];
                stbf(&Eb[0], sx);
                stbf(&Eb[1], sy);
                stbf(&Eb[2], sz);
                stbf(&Eb[3], cx);
                stbf(&Eb[4], cy);
                stbf(&Eb[5], cz);
                if (b < 4) {
                    dbl_angle(&sx, &cx);
                    dbl_angle(&sy, &cy);
                    dbl_angle(&sz, &cz);
                }
            }
        }
        // --- layer 1: h = relu(E @ W1 + b1) ---
        f32x4 acc1[2][4];
        #pragma unroll
        for (int mt = 0; mt < 2; mt++)
            #pragma unroll
            for (int nt = 0; nt < 4; nt++)
                acc1[mt][nt] = (f32x4){0.0f, 0.0f, 0.0f, 0.0f};
        {
            short8 af[2][2];
            #pragma unroll
            for (int mt = 0; mt < 2; mt++)
                #pragma unroll
                for (int kt = 0; kt < 2; kt++)
                    af[mt][kt] = *(const short8*)&myE[(nfr + 16 * mt) * 72 + quad * 8 + kt * 32];
            #pragma unroll
            for (int mt = 0; mt < 2; mt++)
                #pragma unroll
                for (int nt = 0; nt < 4; nt++)
                    #pragma unroll
                    for (int kt = 0; kt < 2; kt++)
                        acc1[mt][nt] = __builtin_amdgcn_mfma_f32_16x16x32_bf16(
                            af[mt][kt], w1f[nt][kt], acc1[mt][nt], 0, 0, 0);
        }
        #pragma unroll
        for (int mt = 0; mt < 2; mt++)
            #pragma unroll
            for (int nt = 0; nt < 4; nt++) {
                const f2 bb = {bb1[nt], bb1[nt]};
                const f2 p0 = max2z((f2){acc1[mt][nt][0], acc1[mt][nt][1]} + bb);
                const f2 p1 = max2z((f2){acc1[mt][nt][2], acc1[mt][nt][3]} + bb);
                const int m0 = 4 * quad + 16 * mt;
                stbf(&myE[(m0 + 0) * 72 + nfr + 16 * nt], p0.x);
                stbf(&myE[(m0 + 1) * 72 + nfr + 16 * nt], p0.y);
                stbf(&myE[(m0 + 2) * 72 + nfr + 16 * nt], p1.x);
                stbf(&myE[(m0 + 3) * 72 + nfr + 16 * nt], p1.y);
            }
        // --- W2: O = h @ W2 + b2 ---
        f32x4 acc2[2];
        acc2[0] = (f32x4){0.0f, 0.0f, 0.0f, 0.0f};
        acc2[1] = (f32x4){0.0f, 0.0f, 0.0f, 0.0f};
        {
            short8 ah[2][2];
            #pragma unroll
            for (int mt = 0; mt < 2; mt++)
                #pragma unroll
                for (int kt = 0; kt < 2; kt++)
                    ah[mt][kt] = *(const short8*)&myE[(nfr + 16 * mt) * 72 + quad * 8 + kt * 32];
            #pragma unroll
            for (int mt = 0; mt < 2; mt++)
                #pragma unroll
                for (int kt = 0; kt < 2; kt++)
                    acc2[mt] = __builtin_amdgcn_mfma_f32_16x16x32_bf16(
                        ah[mt][kt], w2f[kt], acc2[mt], 0, 0, 0);
        }
        if (nfr == 0) {
            #pragma unroll
            for (int mt = 0; mt < 2; mt++)
                #pragma unroll
                for (int r = 0; r < 4; r++) {
                    const int m = 4 * quad + r + 16 * mt;
                    const float sg = fmaxf(acc2[mt][r] + bb2, 0.0f);
                    sOm[wave * 128 + qq * 32 + m] = __expf(-sg * dtv);
                }
        } else {
            #pragma unroll
            for (int mt = 0; mt < 2; mt++) {
                const f2 bb = {bb2, bb2};
                const f2 q0 = (f2){acc2[mt][0], acc2[mt][1]} + bb;
                const f2 q1 = (f2){acc2[mt][2], acc2[mt][3]} + bb;
                const int m0 = 4 * quad + 16 * mt;
                stbf(&myG[(m0 + 0) * 32 + (nfr - 1)], q0.x);
                stbf(&myG[(m0 + 1) * 32 + (nfr - 1)], q0.y);
                stbf(&myG[(m0 + 2) * 32 + (nfr - 1)], q1.x);
                stbf(&myG[(m0 + 3) * 32 + (nfr - 1)], q1.y);
            }
        }
        // --- V1: g = relu(G_in @ V1 + c1 + gvde) ---
        f32x4 acc3[2][4];
        #pragma unroll
        for (int mt = 0; mt < 2; mt++)
            #pragma unroll
            for (int nt = 0; nt < 4; nt++)
                acc3[mt][nt] = (f32x4){0.0f, 0.0f, 0.0f, 0.0f};
        {
            short8 ag[2];
            #pragma unroll
            for (int mt = 0; mt < 2; mt++)
                ag[mt] = *(const short8*)&myG[(nfr + 16 * mt) * 32 + quad * 8];
            #pragma unroll
            for (int mt = 0; mt < 2; mt++)
                #pragma unroll
                for (int nt = 0; nt < 4; nt++)
                    acc3[mt][nt] = __builtin_amdgcn_mfma_f32_16x16x32_bf16(
                        ag[mt], v1f[nt], acc3[mt][nt], 0, 0, 0);
        }
        #pragma unroll
        for (int mt = 0; mt < 2; mt++)
            #pragma unroll
            for (int nt = 0; nt < 4; nt++) {
                const f2 gb = {gadd[nt], gadd[nt]};
                const f2 p0 = max2z((f2){acc3[mt][nt][0], acc3[mt][nt][1]} + gb);
                const f2 p1 = max2z((f2){acc3[mt][nt][2], acc3[mt][nt][3]} + gb);
                const int m0 = 4 * quad + 16 * mt;
                stbf(&myE[(m0 + 0) * 72 + nfr + 16 * nt], p0.x);
                stbf(&myE[(m0 + 1) * 72 + nfr + 16 * nt], p0.y);
                stbf(&myE[(m0 + 2) * 72 + nfr + 16 * nt], p1.x);
                stbf(&myE[(m0 + 3) * 72 + nfr + 16 * nt], p1.y);
            }
        // --- V2: rgb = sigmoid(g @ V2 + c2) ---
        f32x4 acc4[2];
        acc4[0] = (f32x4){0.0f, 0.0f, 0.0f, 0.0f};
        acc4[1] = (f32x4){0.0f, 0.0f, 0.0f, 0.0f};
        {
            short8 agg[2][2];
            #pragma unroll
            for (int mt = 0; mt < 2; mt++)
                #pragma unroll
                for (int kt = 0; kt < 2; kt++)
                    agg[mt][kt] = *(const short8*)&myE[(nfr + 16 * mt) * 72 + quad * 8 + kt * 32];
            #pragma unroll
            for (int mt = 0; mt < 2; mt++)
                #pragma unroll
                for (int kt = 0; kt < 2; kt++)
                    acc4[mt] = __builtin_amdgcn_mfma_f32_16x16x32_bf16(
                        agg[mt][kt], v2f[kt], acc4[mt], 0, 0, 0);
        }
        if (nfr < 3) {
            #pragma unroll
            for (int mt = 0; mt < 2; mt++)
                #pragma unroll
                for (int r = 0; r < 4; r++) {
                    const int m = 4 * quad + r + 16 * mt;
                    const float val = acc4[mt][r] + bc2;
                    stbf(&sRgb[wave * 384 + (qq * 32 + m) * 3 + nfr],
                         1.0f / (1.0f + __expf(-val)));
                }
        }
    }

    // ---- exclusive multiplicative scan + weighted reduce (per wave) ----
    const float om0 = sOm[wave * 128 + 2 * lane];
    const float om1 = sOm[wave * 128 + 2 * lane + 1];
    const float al0 = 1.0f - om0;
    const float al1 = 1.0f - om1;

    float inc = om0 * om1;
    #pragma unroll
    for (int off = 1; off < 64; off <<= 1) {
        const float q = __shfl_up(inc, off, 64);
        if (lane >= off) inc *= q;
    }
    float Texc = __shfl_up(inc, 1, 64);
    if (lane == 0) Texc = 1.0f;

    const float T0 = Texc;
    const float T1 = Texc * om0;
    const float a0 = (T0 > 1e-4f) ? 1.0f : 0.0f;
    const float a1 = (T1 > 1e-4f) ? 1.0f : 0.0f;
    const float w0 = T0 * al0 * a0;
    const float w1 = T1 * al1 * a1;

    float cr = w0 * bf2f(sRgb[wave * 384 + (2 * lane) * 3 + 0]) +
               w1 * bf2f(sRgb[wave * 384 + (2 * lane + 1) * 3 + 0]);
    float cg = w0 * bf2f(sRgb[wave * 384 + (2 * lane) * 3 + 1]) +
               w1 * bf2f(sRgb[wave * 384 + (2 * lane + 1) * 3 + 1]);
    float cb = w0 * bf2f(sRgb[wave * 384 + (2 * lane) * 3 + 2]) +
               w1 * bf2f(sRgb[wave * 384 + (2 * lane + 1) * 3 + 2]);
    float tp = (a0 > 0.0f ? om0 : 1.0f) * (a1 > 0.0f ? om1 : 1.0f);

    #pragma unroll
    for (int off = 32; off > 0; off >>= 1) {
        cr += __shfl_xor(cr, off, 64);
        cg += __shfl_xor(cg, off, 64);
        cb += __shfl_xor(cb, off, 64);
        tp *= __shfl_xor(tp, off, 64);
    }

    if (lane == 0) {
        out[ray * 3 + 0] = cr;
        out[ray * 3 + 1] = cg;
        out[ray * 3 + 2] = cb;
        out[NRAYS * 3 + ray] = tp;
    }
}

extern "C" void kernel_launch(void* const* d_in, const int* in_sizes, int n_in,
                              void* d_out, int out_size, void* d_ws, size_t ws_size,
                              hipStream_t stream) {
    const float* orig = (const float*)d_in[0];
    const float* dirs = (const float*)d_in[1];
    const float* tmin = (const float*)d_in[2];
    const float* tmax = (const float*)d_in[3];
    const float* W1   = (const float*)d_in[4];
    const float* b1   = (const float*)d_in[5];
    const float* W2   = (const float*)d_in[6];
    const float* b2   = (const float*)d_in[7];
    const float* V1   = (const float*)d_in[8];
    const float* c1   = (const float*)d_in[9];
    const float* V2   = (const float*)d_in[10];
    const float* c2   = (const float*)d_in[11];

    march_kernel<<<NRAYS / 4, 256, 0, stream>>>(orig, dirs, tmin, tmax,
                                                W1, b1, W2, b2, V1, c1, V2, c2,
                                                (float*)d_out);
}

// Round 17
// 152.507 us; speedup vs baseline: 1.0730x; 1.0730x over previous
//
#include <hip/hip_runtime.h>
#include <hip/hip_bf16.h>

#define NRAYS 8192
#define SAMP  128
#define DVD   27
#define NFEAT 15

typedef float  f32x4  __attribute__((ext_vector_type(4)));
typedef short  short8 __attribute__((ext_vector_type(8)));

// fast fp32 -> bf16 (round-half-up): store HIGH short of (bits + 0x8000)
static __device__ __forceinline__ void stbf(short* p, float x) {
    union { unsigned u; struct { short lo, hi; } s; } v;
    v.u = __float_as_uint(x) + 0x8000u;
    *p = v.s.hi;
}
static __device__ __forceinline__ float bf2f(short s) {
    return __uint_as_float(((unsigned)(unsigned short)s) << 16);
}
static __device__ __forceinline__ void sincos_fast(float x, float* s, float* c) {
    float r = x * 0.15915494309189535f;
    r = r - floorf(r);
    *s = __builtin_amdgcn_sinf(r);
    *c = __builtin_amdgcn_cosf(r);
}
static __device__ __forceinline__ float sin_fast(float x) {
    float r = x * 0.15915494309189535f;
    r = r - floorf(r);
    return __builtin_amdgcn_sinf(r);
}
static __device__ __forceinline__ float cos_fast(float x) {
    float r = x * 0.15915494309189535f;
    r = r - floorf(r);
    return __builtin_amdgcn_cosf(r);
}

// LDS layout (overlay) — R14-proven best (32208 B, 5 blk/CU):
//   staging (pre-b2): sW1t@0 [64*72]s 9216B, sW2t@9216 [16*72]s 2304B,
//                     sV1t@11520 [64*32]s 4096B, sV2t@15616 [3*72]s 432B
//   working (post-b2): sE@0 [4][32*72]s 18432B, sG@18432 [4][32*32]s 8192B
//   persistent: sOm@26624 [4][128]f 2048B, sRgb@28672 [4][384]s 3072B,
//               sVde@31744 [4][28]f 448B, sRed@32192 [4]f 16B -> 32208 B
#define SMEM_BYTES 32208

__global__ void __launch_bounds__(256)
march_kernel(const float* __restrict__ orig,
             const float* __restrict__ dirs,
             const float* __restrict__ tmin,
             const float* __restrict__ tmax,
             const float* __restrict__ W1,
             const float* __restrict__ b1,
             const float* __restrict__ W2,
             const float* __restrict__ b2,
             const float* __restrict__ V1,
             const float* __restrict__ c1,
             const float* __restrict__ V2,
             const float* __restrict__ c2,
             float* __restrict__ out) {
    __shared__ __align__(16) char smem[SMEM_BYTES];
    short* const sW1t = (short*)(smem);            // [n*72+k], k<63 real
    short* const sW2t = (short*)(smem + 9216);     // [n*72+k]
    short* const sV1t = (short*)(smem + 11520);    // [n*32+k], k<15 real
    short* const sV2t = (short*)(smem + 15616);    // [n*72+k], n<3
    short* const sEa  = (short*)(smem);            // [wave][32*72]
    short* const sGa  = (short*)(smem + 18432);    // [wave][32*32]
    float* const sOm  = (float*)(smem + 26624);    // [wave][128]
    short* const sRgb = (short*)(smem + 28672);    // [wave][384]
    float* const sVde = (float*)(smem + 31744);    // [wave][28]
    float* const sRed = (float*)(smem + 32192);    // [4]

    const int tid  = threadIdx.x;
    const int lane = tid & 63;
    const int wave = tid >> 6;
    const int ray  = blockIdx.x * 4 + wave;

    // ---- block-redundant dt partial: sum(tmax - tmin) ----
    {
        const float4* tm0 = (const float4*)tmin;
        const float4* tm1 = (const float4*)tmax;
        float s = 0.0f;
        #pragma unroll
        for (int it = 0; it < 8; it++) {
            const int i = tid + it * 256;
            const float4 a = tm1[i], b = tm0[i];
            s += (a.x - b.x) + (a.y - b.y) + (a.z - b.z) + (a.w - b.w);
        }
        #pragma unroll
        for (int off = 32; off > 0; off >>= 1)
            s += __shfl_xor(s, off, 64);
        if (lane == 0) sRed[wave] = s;
    }

    // ---- cooperative weight staging (coalesced global reads) ----
    for (int i = tid; i < 63 * 64; i += 256) {   // W1 [63][64]
        const int k = i >> 6, n = i & 63;
        stbf(&sW1t[n * 72 + k], W1[i]);
    }
    for (int i = tid; i < 64; i += 256) sW1t[i * 72 + 63] = 0;  // pad k=63
    for (int i = tid; i < 64 * 16; i += 256) {   // W2 [64][16]
        const int k = i >> 4, n = i & 15;
        stbf(&sW2t[n * 72 + k], W2[i]);
    }
    for (int i = tid; i < 15 * 64; i += 256) {   // V1 [15][64] (feature rows)
        const int k = i >> 6, n = i & 63;
        stbf(&sV1t[n * 32 + k], V1[i]);
    }
    for (int i = tid; i < 64 * 17; i += 256) {   // V1 pad k=15..31
        const int n = i / 17, k = 15 + (i - 17 * n);
        sV1t[n * 32 + k] = 0;
    }
    for (int i = tid; i < 192; i += 256) {       // V2 [64][3]
        const int k = i / 3, n = i - 3 * k;
        stbf(&sV2t[n * 72 + k], V2[i]);
    }

    // ---- per-ray scalars ----
    const float ox = orig[ray * 3 + 0];
    const float oy = orig[ray * 3 + 1];
    const float oz = orig[ray * 3 + 2];
    const float dx = dirs[ray * 3 + 0];
    const float dy = dirs[ray * 3 + 1];
    const float dz = dirs[ray * 3 + 2];
    const float t0v = tmin[ray];
    const float trange = tmax[ray] - t0v;

    // ---- view-dir encoding (fp32) -> sVde (per-wave) ----
    {
        const float nrm = sqrtf(dx * dx + dy * dy + dz * dz);
        const float inv = 1.0f / (nrm + 1e-8f);
        const float vx = dx * inv, vy = dy * inv, vz = dz * inv;
        if (lane < DVD) {
            float val;
            if (lane < 3) {
                val = (lane == 0) ? vx : ((lane == 1) ? vy : vz);
            } else {
                const int q = lane - 3;
                const int b = q / 6;
                const int r = q - 6 * b;
                const bool isSin = (r < 3);
                const int d = isSin ? r : (r - 3);
                const float comp = (d == 0) ? vx : ((d == 1) ? vy : vz);
                const float a = (float)(1 << b) * comp;
                val = isSin ? sin_fast(a) : cos_fast(a);
            }
            sVde[wave * 28 + lane] = val;
        }
    }
    __syncthreads();   // barrier 1: staging + dt reduce complete

    const float dtv = (sRed[0] + sRed[1] + sRed[2] + sRed[3]) *
                      (1.0f / ((float)NRAYS * (float)SAMP));

    const int nfr  = lane & 15;   // n (or m) within a 16-tile
    const int quad = lane >> 4;

    // ---- build B-fragments from LDS staging (ds_read_b128) ----
    short8 w1f[4][2], w2f[2], v1f[4], v2f[2];
    #pragma unroll
    for (int nt = 0; nt < 4; nt++)
        #pragma unroll
        for (int kt = 0; kt < 2; kt++)
            w1f[nt][kt] = *(const short8*)&sW1t[(nfr + 16 * nt) * 72 + quad * 8 + kt * 32];
    #pragma unroll
    for (int kt = 0; kt < 2; kt++)
        w2f[kt] = *(const short8*)&sW2t[nfr * 72 + quad * 8 + kt * 32];
    #pragma unroll
    for (int nt = 0; nt < 4; nt++)
        v1f[nt] = *(const short8*)&sV1t[(nfr + 16 * nt) * 32 + quad * 8];
    #pragma unroll
    for (int kt = 0; kt < 2; kt++) {
        if (nfr < 3)
            v2f[kt] = *(const short8*)&sV2t[nfr * 72 + quad * 8 + kt * 32];
        else
            v2f[kt] = (short8){0, 0, 0, 0, 0, 0, 0, 0};
    }

    // ---- biases into per-lane registers ----
    float bb1[4], bc1[4];
    #pragma unroll
    for (int nt = 0; nt < 4; nt++) {
        bb1[nt] = b1[nfr + 16 * nt];
        bc1[nt] = c1[nfr + 16 * nt];
    }
    const float bb2 = b2[nfr];
    const float bc2 = (nfr < 3) ? c2[nfr] : 0.0f;

    // ---- gvde[n] = sum_q vde[q] * V1[15+q][n] (fp32, per ray) ----
    float gv[4] = {0.0f, 0.0f, 0.0f, 0.0f};
    #pragma unroll 1
    for (int q = 0; q < DVD; q++) {
        const float e = sVde[wave * 28 + q];
        const float* vrow = V1 + (NFEAT + q) * 64;
        #pragma unroll
        for (int nt = 0; nt < 4; nt++) gv[nt] += e * vrow[nfr + 16 * nt];
    }
    __syncthreads();   // barrier 2: fragment reads done before sE overwrite

    short* const myE = sEa + wave * (32 * 72);
    short* const myG = sGa + wave * (32 * 32);
    // zero myG (A-side pad must be finite; LDS is undefined at launch)
    {
        int* gz = (int*)myG;
        for (int i = lane; i < 32 * 16; i += 64) gz[i] = 0;
    }

    const int sl   = lane >> 1;   // local sample 0..31 (enc phase)
    const int half = lane & 1;

    #pragma unroll 1
    for (int qq = 0; qq < 4; qq++) {
        // --- positional encodings for 32 samples (2 lanes/sample) ---
        {
            const int s = qq * 32 + sl;
            const float t = t0v + (float)s * (1.0f / 127.0f) * trange;
            const float px = ox + dx * t, py = oy + dy * t, pz = oz + dz * t;
            short* Erow = &myE[sl * 72];
            if (half == 0) {
                stbf(&Erow[0], px); stbf(&Erow[1], py); stbf(&Erow[2], pz);
                #pragma unroll 1
                for (int b = 0; b < 5; b++) {
                    const float f = (float)(1 << b);
                    float sx, cx, sy, cy, sz, cz;
                    sincos_fast(f * px, &sx, &cx);
                    sincos_fast(f * py, &sy, &cy);
                    sincos_fast(f * pz, &sz, &cz);
                    stbf(&Erow[3 + 6 * b + 0], sx);
                    stbf(&Erow[3 + 6 * b + 1], sy);
                    stbf(&Erow[3 + 6 * b + 2], sz);
                    stbf(&Erow[3 + 6 * b + 3], cx);
                    stbf(&Erow[3 + 6 * b + 4], cy);
                    stbf(&Erow[3 + 6 * b + 5], cz);
                }
            } else {
                #pragma unroll 1
                for (int b = 5; b < 10; b++) {
                    const float f = (float)(1 << b);
                    float sx, cx, sy, cy, sz, cz;
                    sincos_fast(f * px, &sx, &cx);
                    sincos_fast(f * py, &sy, &cy);
                    sincos_fast(f * pz, &sz, &cz);
                    stbf(&Erow[3 + 6 * b + 0], sx);
                    stbf(&Erow[3 + 6 * b + 1], sy);
                    stbf(&Erow[3 + 6 * b + 2], sz);
                    stbf(&Erow[3 + 6 * b + 3], cx);
                    stbf(&Erow[3 + 6 * b + 4], cy);
                    stbf(&Erow[3 + 6 * b + 5], cz);
                }
                Erow[63] = 0;
            }
        }
        // --- layer 1: h = relu(E @ W1 + b1) ---
        f32x4 acc1[2][4];
        #pragma unroll
        for (int mt = 0; mt < 2; mt++)
            #pragma unroll
            for (int nt = 0; nt < 4; nt++)
                acc1[mt][nt] = (f32x4){0.0f, 0.0f, 0.0f, 0.0f};
        {
            short8 af[2][2];
            #pragma unroll
            for (int mt = 0; mt < 2; mt++)
                #pragma unroll
                for (int kt = 0; kt < 2; kt++)
                    af[mt][kt] = *(const short8*)&myE[(nfr + 16 * mt) * 72 + quad * 8 + kt * 32];
            #pragma unroll
            for (int mt = 0; mt < 2; mt++)
                #pragma unroll
                for (int nt = 0; nt < 4; nt++)
                    #pragma unroll
                    for (int kt = 0; kt < 2; kt++)
                        acc1[mt][nt] = __builtin_amdgcn_mfma_f32_16x16x32_bf16(
                            af[mt][kt], w1f[nt][kt], acc1[mt][nt], 0, 0, 0);
        }
        #pragma unroll
        for (int mt = 0; mt < 2; mt++)
            #pragma unroll
            for (int nt = 0; nt < 4; nt++)
                #pragma unroll
                for (int r = 0; r < 4; r++) {
                    const int m = 4 * quad + r + 16 * mt;
                    const float hv = fmaxf(acc1[mt][nt][r] + bb1[nt], 0.0f);
                    stbf(&myE[m * 72 + nfr + 16 * nt], hv);
                }
        // --- W2: O = h @ W2 + b2 ---
        f32x4 acc2[2];
        acc2[0] = (f32x4){0.0f, 0.0f, 0.0f, 0.0f};
        acc2[1] = (f32x4){0.0f, 0.0f, 0.0f, 0.0f};
        {
            short8 ah[2][2];
            #pragma unroll
            for (int mt = 0; mt < 2; mt++)
                #pragma unroll
                for (int kt = 0; kt < 2; kt++)
                    ah[mt][kt] = *(const short8*)&myE[(nfr + 16 * mt) * 72 + quad * 8 + kt * 32];
            #pragma unroll
            for (int mt = 0; mt < 2; mt++)
                #pragma unroll
                for (int kt = 0; kt < 2; kt++)
                    acc2[mt] = __builtin_amdgcn_mfma_f32_16x16x32_bf16(
                        ah[mt][kt], w2f[kt], acc2[mt], 0, 0, 0);
        }
        if (nfr == 0) {
            #pragma unroll
            for (int mt = 0; mt < 2; mt++)
                #pragma unroll
                for (int r = 0; r < 4; r++) {
                    const int m = 4 * quad + r + 16 * mt;
                    const float sg = fmaxf(acc2[mt][r] + bb2, 0.0f);
                    sOm[wave * 128 + qq * 32 + m] = __expf(-sg * dtv);
                }
        } else {
            #pragma unroll
            for (int mt = 0; mt < 2; mt++)
                #pragma unroll
                for (int r = 0; r < 4; r++) {
                    const int m = 4 * quad + r + 16 * mt;
                    stbf(&myG[m * 32 + (nfr - 1)], acc2[mt][r] + bb2);
                }
        }
        // --- V1: g = relu(G_in @ V1 + c1 + gvde) ---
        f32x4 acc3[2][4];
        #pragma unroll
        for (int mt = 0; mt < 2; mt++)
            #pragma unroll
            for (int nt = 0; nt < 4; nt++)
                acc3[mt][nt] = (f32x4){0.0f, 0.0f, 0.0f, 0.0f};
        {
            short8 ag[2];
            #pragma unroll
            for (int mt = 0; mt < 2; mt++)
                ag[mt] = *(const short8*)&myG[(nfr + 16 * mt) * 32 + quad * 8];
            #pragma unroll
            for (int mt = 0; mt < 2; mt++)
                #pragma unroll
                for (int nt = 0; nt < 4; nt++)
                    acc3[mt][nt] = __builtin_amdgcn_mfma_f32_16x16x32_bf16(
                        ag[mt], v1f[nt], acc3[mt][nt], 0, 0, 0);
        }
        #pragma unroll
        for (int mt = 0; mt < 2; mt++)
            #pragma unroll
            for (int nt = 0; nt < 4; nt++)
                #pragma unroll
                for (int r = 0; r < 4; r++) {
                    const int m = 4 * quad + r + 16 * mt;
                    const float gval = fmaxf(acc3[mt][nt][r] + bc1[nt] + gv[nt], 0.0f);
                    stbf(&myE[m * 72 + nfr + 16 * nt], gval);
                }
        // --- V2: rgb = sigmoid(g @ V2 + c2) ---
        f32x4 acc4[2];
        acc4[0] = (f32x4){0.0f, 0.0f, 0.0f, 0.0f};
        acc4[1] = (f32x4){0.0f, 0.0f, 0.0f, 0.0f};
        {
            short8 agg[2][2];
            #pragma unroll
            for (int mt = 0; mt < 2; mt++)
                #pragma unroll
                for (int kt = 0; kt < 2; kt++)
                    agg[mt][kt] = *(const short8*)&myE[(nfr + 16 * mt) * 72 + quad * 8 + kt * 32];
            #pragma unroll
            for (int mt = 0; mt < 2; mt++)
                #pragma unroll
                for (int kt = 0; kt < 2; kt++)
                    acc4[mt] = __builtin_amdgcn_mfma_f32_16x16x32_bf16(
                        agg[mt][kt], v2f[kt], acc4[mt], 0, 0, 0);
        }
        if (nfr < 3) {
            #pragma unroll
            for (int mt = 0; mt < 2; mt++)
                #pragma unroll
                for (int r = 0; r < 4; r++) {
                    const int m = 4 * quad + r + 16 * mt;
                    const float val = acc4[mt][r] + bc2;
                    stbf(&sRgb[wave * 384 + (qq * 32 + m) * 3 + nfr],
                         1.0f / (1.0f + __expf(-val)));
                }
        }
    }

    // ---- exclusive multiplicative scan + weighted reduce (per wave) ----
    const float om0 = sOm[wave * 128 + 2 * lane];
    const float om1 = sOm[wave * 128 + 2 * lane + 1];
    const float al0 = 1.0f - om0;
    const float al1 = 1.0f - om1;

    float inc = om0 * om1;
    #pragma unroll
    for (int off = 1; off < 64; off <<= 1) {
        const float q = __shfl_up(inc, off, 64);
        if (lane >= off) inc *= q;
    }
    float Texc = __shfl_up(inc, 1, 64);
    if (lane == 0) Texc = 1.0f;

    const float T0 = Texc;
    const float T1 = Texc * om0;
    const float a0 = (T0 > 1e-4f) ? 1.0f : 0.0f;
    const float a1 = (T1 > 1e-4f) ? 1.0f : 0.0f;
    const float w0 = T0 * al0 * a0;
    const float w1 = T1 * al1 * a1;

    float cr = w0 * bf2f(sRgb[wave * 384 + (2 * lane) * 3 + 0]) +
               w1 * bf2f(sRgb[wave * 384 + (2 * lane + 1) * 3 + 0]);
    float cg = w0 * bf2f(sRgb[wave * 384 + (2 * lane) * 3 + 1]) +
               w1 * bf2f(sRgb[wave * 384 + (2 * lane + 1) * 3 + 1]);
    float cb = w0 * bf2f(sRgb[wave * 384 + (2 * lane) * 3 + 2]) +
               w1 * bf2f(sRgb[wave * 384 + (2 * lane + 1) * 3 + 2]);
    float tp = (a0 > 0.0f ? om0 : 1.0f) * (a1 > 0.0f ? om1 : 1.0f);

    #pragma unroll
    for (int off = 32; off > 0; off >>= 1) {
        cr += __shfl_xor(cr, off, 64);
        cg += __shfl_xor(cg, off, 64);
        cb += __shfl_xor(cb, off, 64);
        tp *= __shfl_xor(tp, off, 64);
    }

    if (lane == 0) {
        out[ray * 3 + 0] = cr;
        out[ray * 3 + 1] = cg;
        out[ray * 3 + 2] = cb;
        out[NRAYS * 3 + ray] = tp;
    }
}

extern "C" void kernel_launch(void* const* d_in, const int* in_sizes, int n_in,
                              void* d_out, int out_size, void* d_ws, size_t ws_size,
                              hipStream_t stream) {
    const float* orig = (const float*)d_in[0];
    const float* dirs = (const float*)d_in[1];
    const float* tmin = (const float*)d_in[2];
    const float* tmax = (const float*)d_in[3];
    const float* W1   = (const float*)d_in[4];
    const float* b1   = (const float*)d_in[5];
    const float* W2   = (const float*)d_in[6];
    const float* b2   = (const float*)d_in[7];
    const float* V1   = (const float*)d_in[8];
    const float* c1   = (const float*)d_in[9];
    const float* V2   = (const float*)d_in[10];
    const float* c2   = (const float*)d_in[11];

    march_kernel<<<NRAYS / 4, 256, 0, stream>>>(orig, dirs, tmin, tmax,
                                                W1, b1, W2, b2, V1, c1, V2, c2,
                                                (float*)d_out);
}